// Round 21
// baseline (118.854 us; speedup 1.0000x reference)
//
#include <hip/hip_runtime.h>
#include <hip/hip_bf16.h>
#include <math.h>

#define B_ 64
#define P_ 2048
#define E_ 512
#define H_ 8
#define D_ 1024
#define NC_ 32     // stat chunks of 64 p
#define NG_ 4      // apart groups (one per persistent block per b)
// LDS: kswz[2] u16[64][512] 2x65536 | scr f32[2][16][68]=8704 | wbf u16[16][72]=2304 | fac 64 | mrun 64
#define SMEM_FUSED (131072 + 8704 + 2304 + 64 + 64)

// raw barrier: sched_barrier pins LDS op order; lgkm-only drain
#define BAR() do { __builtin_amdgcn_sched_barrier(0); \
                   asm volatile("s_waitcnt lgkmcnt(0)"); \
                   __builtin_amdgcn_s_barrier(); \
                   __builtin_amdgcn_sched_barrier(0); } while (0)

// full row-XOR for kswz (u16-index space): 2-way max bank aliasing in all phases
#define KXOR(row) ((((row) & 7) << 3) ^ (((row) & 8) << 1) ^ (((row) & 16) >> 1))

static constexpr float SCALING_C = 0.125f;
static constexpr float LAMBDA_INIT_C = 0.35550906759096966f;

typedef float f32x4 __attribute__((ext_vector_type(4)));
typedef float f32x2 __attribute__((ext_vector_type(2)));
typedef short bf16x8 __attribute__((ext_vector_type(8)));
typedef short bf16x4 __attribute__((ext_vector_type(4)));

// HW bf16 convert (RNE)
static __device__ __forceinline__ short f2bf(float f) {
    __hip_bfloat16 h = __float2bfloat16(f);
    return __builtin_bit_cast(short, h);
}
static __device__ __forceinline__ float bf2f(unsigned short s) {
    return __builtin_bit_cast(float, (unsigned)s << 16);
}

// ---------- qproj: qhat slice then qk B-fragments ----------
__global__ __launch_bounds__(256) void k_qproj(const float* __restrict__ query,
                                               const float* __restrict__ Wq,
                                               const float* __restrict__ Wk,
                                               unsigned short* __restrict__ qkfrag) {
    int x = blockIdx.x, b = blockIdx.y, t = threadIdx.x;
    __shared__ float q[E_];
    __shared__ float qh[256];
    q[t] = query[b * E_ + t];
    q[t + 256] = query[b * E_ + t + 256];
    __syncthreads();
    {
        int j = x * 256 + t;
        const float* w = Wq + j;
        float s[8] = {0.f,0.f,0.f,0.f,0.f,0.f,0.f,0.f};
        #pragma unroll 4
        for (int e = 0; e < E_; e += 8) {
            #pragma unroll
            for (int k = 0; k < 8; ++k) s[k] += q[e + k] * w[(long)(e + k) * D_];
        }
        qh[t] = (((s[0]+s[1])+(s[2]+s[3])) + ((s[4]+s[5])+(s[6]+s[7]))) * SCALING_C;
    }
    __syncthreads();
    int hs_loc = t >> 6, l = t & 63;
    int hs = x * 4 + hs_loc;
    int e0 = l * 8;
    const float* qp = qh + hs_loc * 64;
    float acc[8];
    #pragma unroll
    for (int jj = 0; jj < 8; ++jj) {
        const f32x4* w = (const f32x4*)(Wk + (long)(e0 + jj) * D_ + hs * 64);
        float s = 0.f;
        #pragma unroll
        for (int d4 = 0; d4 < 16; ++d4) {
            f32x4 wv = w[d4];
            s += qp[d4 * 4 + 0] * wv[0] + qp[d4 * 4 + 1] * wv[1]
               + qp[d4 * 4 + 2] * wv[2] + qp[d4 * 4 + 3] * wv[3];
        }
        acc[jj] = s;
    }
    bf16x8 v;
    #pragma unroll
    for (int jj = 0; jj < 8; ++jj) v[jj] = f2bf(acc[jj]);
    *(bf16x8*)(qkfrag + (((long)b * 16 + (l >> 2)) * 64 + (l & 3) * 16 + hs) * 8) = v;
}

// ---------- persistent fused: double-buffered kswz, 3 barriers/chunk ----------
__global__ __launch_bounds__(512, 2) void k_fusedp(const float* __restrict__ key,
                                                   const unsigned short* __restrict__ qkfrag,
                                                   unsigned short* __restrict__ wexp,
                                                   float* __restrict__ ms, float* __restrict__ zs,
                                                   unsigned short* __restrict__ apart) {
    extern __shared__ __align__(16) char smem[];
    float* scr           = (float*)(smem + 131072);          // [2 eh][16 hs][68 p]
    unsigned short* wbf  = (unsigned short*)(smem + 139776); // [16 hs][72 p]
    float* fac_l         = (float*)(smem + 142080);          // [16]
    float* mrun_l        = (float*)(smem + 142144);          // [16]

    int pcg = blockIdx.x, b = blockIdx.y;
    int t = threadIdx.x, wv = t >> 6, l = t & 63;
    int rt = wv >> 1, eh = wv & 1;
    int prow = rt * 16 + (l & 15);
    int xorv = KXOR(prow);
    int hi = t >> 7;          // row = 4r + hi
    int col4 = t & 127;       // f32x4 column within row

    if (t < 16) mrun_l[t] = -3.0e38f;

    // preload qk B-fragments for this wave's e-half
    bf16x8 qfr[8];
    {
        const bf16x8* qf = (const bf16x8*)(qkfrag + (long)b * 16 * 64 * 8);
        #pragma unroll
        for (int s = 0; s < 8; ++s) qfr[s] = qf[(eh * 8 + s) * 64 + l];
    }

    const float* kchunk = key + ((long)b * P_ + pcg * 512) * E_;

    // prologue: stage chunk 0 (linear contiguous)
    f32x4 x[16];
    #pragma unroll
    for (int r = 0; r < 16; ++r)
        x[r] = *(const f32x4*)(kchunk + (long)(r * 512 + t) * 4);

    f32x4 accp[4];
    #pragma unroll
    for (int i = 0; i < 4; ++i) accp[i] = {0.f, 0.f, 0.f, 0.f};

    for (int c = 0; c < 8; ++c) {
        unsigned short* kz = (unsigned short*)(smem + (c & 1) * 65536);
        // ---- A1: convert + write kz (lane-linear, conflict-free) ----
        #pragma unroll
        for (int r = 0; r < 16; ++r) {
            int row = 4 * r + hi;
            int xr = KXOR(row);
            bf16x4 wb;
            wb[0] = f2bf(x[r][0]); wb[1] = f2bf(x[r][1]);
            wb[2] = f2bf(x[r][2]); wb[3] = f2bf(x[r][3]);
            *(bf16x4*)(kz + row * 512 + ((col4 * 4) ^ xr)) = wb;
        }
        // ---- issue chunk c+1 loads (contiguous; stream under A2/B/C) ----
        if (c < 7) {
            const float* kn = kchunk + (long)(c + 1) * 64 * E_;
            #pragma unroll
            for (int r = 0; r < 16; ++r)
                x[r] = *(const f32x4*)(kn + (long)(r * 512 + t) * 4);
        }
        BAR();

        // ---- A2: QK^T from LDS A-frags ----
        {
            f32x4 acc = {0.f, 0.f, 0.f, 0.f};
            #pragma unroll
            for (int s = 0; s < 8; ++s) {
                int e8 = eh * 256 + (l >> 4) * 8 + s * 32;
                bf16x8 a = *(const bf16x8*)(kz + prow * 512 + (e8 ^ xorv));
                acc = __builtin_amdgcn_mfma_f32_16x16x32_bf16(a, qfr[s], acc, 0, 0, 0);
            }
            #pragma unroll
            for (int r = 0; r < 4; ++r)
                scr[eh * 1088 + (l & 15) * 68 + rt * 16 + (l >> 4) * 4 + r] = acc[r];
        }
        BAR();

        // ---- B: chunk softmax stats + wexp bf16 + wbf bf16 (running-max scaled) ----
        {
            int hs = t >> 5, i = t & 31;
            const float* s0p = scr + hs * 68 + i * 2;
            const float* s1p = s0p + 1088;
            float v0 = s0p[0] + s1p[0];
            float v1 = s0p[1] + s1p[1];
            float m = fmaxf(v0, v1);
            #pragma unroll
            for (int o = 16; o > 0; o >>= 1) m = fmaxf(m, __shfl_xor(m, o));
            float e0v = expf(v0 - m), e1v = expf(v1 - m);
            float z = e0v + e1v;
            #pragma unroll
            for (int o = 16; o > 0; o >>= 1) z += __shfl_xor(z, o);
            float mold = mrun_l[hs];
            float mnew = fmaxf(mold, m);
            float wsc = expf(m - mnew);
            if (i == 0) {
                mrun_l[hs] = mnew;
                fac_l[hs] = expf(mold - mnew);
                ms[((long)(pcg * 8 + c) * B_ + b) * 16 + hs] = m;
                zs[((long)(pcg * 8 + c) * B_ + b) * 16 + hs] = z;
            }
            unsigned wpack = (unsigned)(unsigned short)f2bf(e0v)
                           | ((unsigned)(unsigned short)f2bf(e1v) << 16);
            *(unsigned*)(wexp + ((long)b * 16 + hs) * P_ + pcg * 512 + c * 64 + i * 2) = wpack;
            unsigned lo = (unsigned short)f2bf(e0v * wsc);
            unsigned hi2 = (unsigned short)f2bf(e1v * wsc);
            *(unsigned*)(wbf + hs * 72 + i * 2) = lo | (hi2 << 16);
        }
        BAR();

        // ---- C: PV-MFMA from LDS, reg accum with online rescale (no trailing BAR) ----
        {
            f32x4 frv;
            frv[0] = fac_l[(l >> 4) * 4 + 0];
            frv[1] = fac_l[(l >> 4) * 4 + 1];
            frv[2] = fac_l[(l >> 4) * 4 + 2];
            frv[3] = fac_l[(l >> 4) * 4 + 3];
            const unsigned short* wrow = wbf + (l & 15) * 72;
            bf16x8 af0 = *(const bf16x8*)(wrow + (l >> 4) * 8);
            bf16x8 af1 = *(const bf16x8*)(wrow + 32 + (l >> 4) * 8);
            #pragma unroll
            for (int tile = 0; tile < 4; ++tile) {
                accp[tile] = accp[tile] * frv;
                int e = wv * 64 + tile * 16 + (l & 15);
                #pragma unroll
                for (int ks = 0; ks < 2; ++ks) {
                    int pbase = ks * 32 + (l >> 4) * 8;
                    bf16x8 af = ks ? af1 : af0;
                    int xc = ((pbase & 8) << 1) ^ ((pbase & 16) >> 1);
                    bf16x8 bfv;
                    #pragma unroll
                    for (int j = 0; j < 8; ++j)
                        bfv[j] = (short)kz[(pbase + j) * 512 + (e ^ (j << 3) ^ xc)];
                    accp[tile] = __builtin_amdgcn_mfma_f32_16x16x32_bf16(af, bfv, accp[tile], 0, 0, 0);
                }
            }
        }
        // no barrier: next A1 writes the other kswz buffer
    }

    // ---- epilogue: write group partials as bf16 (relative to group running max) ----
    {
        long abase = ((long)pcg * B_ + b) * 16 * E_;
        #pragma unroll
        for (int tile = 0; tile < 4; ++tile) {
            int e = wv * 64 + tile * 16 + (l & 15);
            #pragma unroll
            for (int r = 0; r < 4; ++r)
                apart[abase + (long)((l >> 4) * 4 + r) * E_ + e] =
                    (unsigned short)f2bf(accp[tile][r]);
        }
    }
}

// ---------- combine: global stats, out1 (diff), attk from 4 groups, OV, RMS -> on ----------
__global__ __launch_bounds__(256) void k_comb(const unsigned short* __restrict__ wexp,
                                              const float* __restrict__ ms, const float* __restrict__ zs,
                                              const unsigned short* __restrict__ apart,
                                              const float* __restrict__ lq1, const float* __restrict__ lk1,
                                              const float* __restrict__ lq2, const float* __restrict__ lk2,
                                              const float* __restrict__ Wv, const float* __restrict__ rmsw,
                                              float* __restrict__ out1, float* __restrict__ on) {
    int h = blockIdx.x, b = blockIdx.y, t = threadIdx.x;
    __shared__ float lam_s;
    __shared__ float mc0s[NC_], mc1s[NC_], zc0s[NC_], zc1s[NC_];
    __shared__ float c0s[NC_], c1s[NC_];
    __shared__ float attk[E_];
    __shared__ float onred[2][128];
    __shared__ float red[4];
    int hs0 = 2 * h, hs1 = 2 * h + 1;
    if (t < 64) {
        float v1 = lq1[t] * lk1[t];
        float v2 = lq2[t] * lk2[t];
        #pragma unroll
        for (int o = 32; o > 0; o >>= 1) { v1 += __shfl_xor(v1, o); v2 += __shfl_xor(v2, o); }
        if (t == 0) lam_s = expf(v1) - expf(v2) + LAMBDA_INIT_C;
    }
    if (t >= 64 && t < 64 + NC_) {
        int c = t - 64;
        mc0s[c] = ms[((long)c * B_ + b) * 16 + hs0];
        mc1s[c] = ms[((long)c * B_ + b) * 16 + hs1];
        zc0s[c] = zs[((long)c * B_ + b) * 16 + hs0];
        zc1s[c] = zs[((long)c * B_ + b) * 16 + hs1];
    }
    __syncthreads();
    float m0 = -3.0e38f, m1 = -3.0e38f;
    #pragma unroll
    for (int c = 0; c < NC_; ++c) { m0 = fmaxf(m0, mc0s[c]); m1 = fmaxf(m1, mc1s[c]); }
    float z0 = 0.f, z1 = 0.f;
    #pragma unroll
    for (int c = 0; c < NC_; ++c) {
        z0 += zc0s[c] * expf(mc0s[c] - m0);
        z1 += zc1s[c] * expf(mc1s[c] - m1);
    }
    float lam = lam_s;
    float i0 = 1.f / (z0 + 1e-20f);
    float i1 = lam / (z1 + 1e-20f);
    if (t < NC_) {
        c0s[t] = expf(mc0s[t] - m0) * i0;
        c1s[t] = expf(mc1s[t] - m1) * i1;
    }
    __syncthreads();
    // out1 = diff (wexp bf16-packed; p0 even and p0+1 share the same 64-chunk)
    const unsigned* w0p = (const unsigned*)(wexp + ((long)b * 16 + hs0) * P_);
    const unsigned* w1p = (const unsigned*)(wexp + ((long)b * 16 + hs1) * P_);
    float* dst = out1 + ((long)b * H_ + h) * P_;
    #pragma unroll
    for (int k4 = 0; k4 < 4; ++k4) {
        int idx = k4 * 256 + t;          // u32 index, p0 = 2*idx
        unsigned w0 = w0p[idx], w1 = w1p[idx];
        int p0 = idx * 2;
        int cc = p0 >> 6;
        dst[p0]     = bf2f((unsigned short)w0) * c0s[cc] - bf2f((unsigned short)w1) * c1s[cc];
        dst[p0 + 1] = bf2f((unsigned short)(w0 >> 16)) * c0s[cc]
                    - bf2f((unsigned short)(w1 >> 16)) * c1s[cc];
    }
    // group weights: m_g = max of the group's 8 chunk maxes
    float cg0[NG_], cg1[NG_];
    #pragma unroll
    for (int g = 0; g < NG_; ++g) {
        float mg0 = -3.0e38f, mg1 = -3.0e38f;
        #pragma unroll
        for (int q = 0; q < 8; ++q) {
            mg0 = fmaxf(mg0, mc0s[g * 8 + q]);
            mg1 = fmaxf(mg1, mc1s[g * 8 + q]);
        }
        cg0[g] = expf(mg0 - m0) * i0;
        cg1[g] = expf(mg1 - m1) * i1;
    }
    #pragma unroll
    for (int k = 0; k < 2; ++k) {
        int e = k * 256 + t;
        float s = 0.f;
        #pragma unroll
        for (int g = 0; g < NG_; ++g) {
            long gb = ((long)g * B_ + b) * 16 * E_;
            s += cg0[g] * bf2f(apart[gb + (long)hs0 * E_ + e])
               - cg1[g] * bf2f(apart[gb + (long)hs1 * E_ + e]);
        }
        attk[e] = s;
    }
    __syncthreads();
    // OV + RMS (8-deep ILP)
    int j = t & 127, half = t >> 7;
    const float* w = Wv + (long)(half * 256) * D_ + h * 128 + j;
    const float* aa = attk + half * 256;
    float s[8] = {0.f,0.f,0.f,0.f,0.f,0.f,0.f,0.f};
    #pragma unroll 4
    for (int e = 0; e < 256; e += 8) {
        #pragma unroll
        for (int k = 0; k < 8; ++k) s[k] += aa[e + k] * w[(long)(e + k) * D_];
    }
    onred[half][j] = ((s[0]+s[1])+(s[2]+s[3])) + ((s[4]+s[5])+(s[6]+s[7]));
    __syncthreads();
    float v = 0.f;
    if (t < 128) v = onred[0][t] + onred[1][t];
    float sq = v * v;
    int wv2 = t >> 6, ln = t & 63;
    #pragma unroll
    for (int o = 32; o > 0; o >>= 1) sq += __shfl_xor(sq, o);
    if (ln == 0) red[wv2] = sq;
    __syncthreads();
    float tot = red[0] + red[1];
    float scale = rsqrtf(tot * (1.f / 128.f) + 1e-5f) * (1.f - LAMBDA_INIT_C);
    if (t < 128) on[(long)b * D_ + h * 128 + t] = v * scale * rmsw[t];
}

// ---------- Wo split-K=2 partials: wop[kc][b][o] ----------
__global__ __launch_bounds__(256) void k_wo(const float* __restrict__ on,
                                            const float* __restrict__ Wo,
                                            float* __restrict__ wop) {
    int kc = blockIdx.x >> 1, oc = blockIdx.x & 1, b = blockIdx.y;
    int t = threadIdx.x;
    __shared__ float sh[512];
    sh[t] = on[(long)b * D_ + kc * 512 + t];
    sh[t + 256] = on[(long)b * D_ + kc * 512 + t + 256];
    __syncthreads();
    int o = oc * 256 + t;
    const float* w = Wo + (long)(kc * 512) * 512 + o;
    float s[8] = {0.f,0.f,0.f,0.f,0.f,0.f,0.f,0.f};
    #pragma unroll 4
    for (int k = 0; k < 512; k += 8) {
        #pragma unroll
        for (int q = 0; q < 8; ++q) s[q] += sh[k + q] * w[(long)(k + q) * 512];
    }
    wop[((long)kc * B_ + b) * 512 + o] = ((s[0]+s[1])+(s[2]+s[3])) + ((s[4]+s[5])+(s[6]+s[7]));
}

// ---------- reduce Wo partials (2-way) -> out0 ----------
__global__ __launch_bounds__(256) void k_wored(const float* __restrict__ wop,
                                               float* __restrict__ out0) {
    int b = blockIdx.x, t = threadIdx.x;
    #pragma unroll
    for (int i = 0; i < 2; ++i) {
        int o = i * 256 + t;
        out0[(long)b * 512 + o] = wop[((long)0 * B_ + b) * 512 + o]
                                + wop[((long)1 * B_ + b) * 512 + o];
    }
}

extern "C" void kernel_launch(void* const* d_in, const int* in_sizes, int n_in,
                              void* d_out, int out_size, void* d_ws, size_t ws_size,
                              hipStream_t stream) {
    const float* query = (const float*)d_in[0];
    const float* key   = (const float*)d_in[1];
    const float* Wq    = (const float*)d_in[2];
    const float* Wk    = (const float*)d_in[3];
    const float* Wv    = (const float*)d_in[4];
    const float* Wo    = (const float*)d_in[5];
    const float* lq1   = (const float*)d_in[6];
    const float* lk1   = (const float*)d_in[7];
    const float* lq2   = (const float*)d_in[8];
    const float* lk2   = (const float*)d_in[9];
    const float* rmsw  = (const float*)d_in[10];

    float* out0 = (float*)d_out;           // [64,1,512]
    float* out1 = out0 + B_ * E_;          // diff_attn [64,8,1,2048]

    // ws (floats): qkfrag slack [262144] | wexp u16 (=1048576 f) | apart u16 (=1048576 f) |
    //              ms[32][64][16] | zs | on | wop[2][64][512]
    unsigned short* qkfrag = (unsigned short*)d_ws;
    unsigned short* wexp  = (unsigned short*)((float*)d_ws + 262144);
    unsigned short* apart = (unsigned short*)((float*)d_ws + 262144 + 1048576);
    float* ms    = (float*)d_ws + 262144 + 1048576 + 1048576;
    float* zs    = ms + NC_ * B_ * 16;
    float* on    = zs + NC_ * B_ * 16;
    float* wop   = on + B_ * D_;

    hipFuncSetAttribute((const void*)k_fusedp,
                        hipFuncAttributeMaxDynamicSharedMemorySize, SMEM_FUSED);

    hipLaunchKernelGGL(k_qproj,  dim3(4, B_),   dim3(256), 0, stream, query, Wq, Wk, qkfrag);
    hipLaunchKernelGGL(k_fusedp, dim3(NG_, B_), dim3(512), SMEM_FUSED, stream,
                       key, qkfrag, wexp, ms, zs, apart);
    hipLaunchKernelGGL(k_comb,   dim3(H_, B_),  dim3(256), 0, stream, wexp, ms, zs, apart,
                       lq1, lk1, lq2, lk2, Wv, rmsw, out1, on);
    hipLaunchKernelGGL(k_wo,     dim3(4, B_),   dim3(256), 0, stream, on, Wo, wop);
    hipLaunchKernelGGL(k_wored,  dim3(B_),      dim3(256), 0, stream, wop, out0);
}

// Round 22
// 117.821 us; speedup vs baseline: 1.0088x; 1.0088x over previous
//
#include <hip/hip_runtime.h>
#include <hip/hip_bf16.h>
#include <math.h>

#define B_ 64
#define P_ 2048
#define E_ 512
#define H_ 8
#define D_ 1024
#define NC_ 32     // stat chunks of 64 p
#define NG_ 4      // apart groups (one per persistent block per b)
// LDS: kswz[2] u16[64][512] 2x65536 | scr f32[2][16][68]=8704 | wbf u16[16][72]=2304 | fac 64 | mrun 64
#define SMEM_FUSED (131072 + 8704 + 2304 + 64 + 64)

// raw barrier: sched_barrier pins LDS op order; lgkm-only drain
#define BAR() do { __builtin_amdgcn_sched_barrier(0); \
                   asm volatile("s_waitcnt lgkmcnt(0)"); \
                   __builtin_amdgcn_s_barrier(); \
                   __builtin_amdgcn_sched_barrier(0); } while (0)

// full row-XOR for kswz (u16-index space): 2-way max bank aliasing in all phases
#define KXOR(row) ((((row) & 7) << 3) ^ (((row) & 8) << 1) ^ (((row) & 16) >> 1))

static constexpr float SCALING_C = 0.125f;
static constexpr float LAMBDA_INIT_C = 0.35550906759096966f;

typedef float f32x4 __attribute__((ext_vector_type(4)));
typedef float f32x2 __attribute__((ext_vector_type(2)));
typedef short bf16x8 __attribute__((ext_vector_type(8)));
typedef short bf16x4 __attribute__((ext_vector_type(4)));

// HW bf16 convert (RNE)
static __device__ __forceinline__ short f2bf(float f) {
    __hip_bfloat16 h = __float2bfloat16(f);
    return __builtin_bit_cast(short, h);
}
static __device__ __forceinline__ float bf2f(unsigned short s) {
    return __builtin_bit_cast(float, (unsigned)s << 16);
}

// ---------- qproj: qhat slice then qk B-fragments ----------
__global__ __launch_bounds__(256) void k_qproj(const float* __restrict__ query,
                                               const float* __restrict__ Wq,
                                               const float* __restrict__ Wk,
                                               unsigned short* __restrict__ qkfrag) {
    int x = blockIdx.x, b = blockIdx.y, t = threadIdx.x;
    __shared__ float q[E_];
    __shared__ float qh[256];
    q[t] = query[b * E_ + t];
    q[t + 256] = query[b * E_ + t + 256];
    __syncthreads();
    {
        int j = x * 256 + t;
        const float* w = Wq + j;
        float s[8] = {0.f,0.f,0.f,0.f,0.f,0.f,0.f,0.f};
        #pragma unroll 4
        for (int e = 0; e < E_; e += 8) {
            #pragma unroll
            for (int k = 0; k < 8; ++k) s[k] += q[e + k] * w[(long)(e + k) * D_];
        }
        qh[t] = (((s[0]+s[1])+(s[2]+s[3])) + ((s[4]+s[5])+(s[6]+s[7]))) * SCALING_C;
    }
    __syncthreads();
    int hs_loc = t >> 6, l = t & 63;
    int hs = x * 4 + hs_loc;
    int e0 = l * 8;
    const float* qp = qh + hs_loc * 64;
    float acc[8];
    #pragma unroll
    for (int jj = 0; jj < 8; ++jj) {
        const f32x4* w = (const f32x4*)(Wk + (long)(e0 + jj) * D_ + hs * 64);
        float s = 0.f;
        #pragma unroll
        for (int d4 = 0; d4 < 16; ++d4) {
            f32x4 wv = w[d4];
            s += qp[d4 * 4 + 0] * wv[0] + qp[d4 * 4 + 1] * wv[1]
               + qp[d4 * 4 + 2] * wv[2] + qp[d4 * 4 + 3] * wv[3];
        }
        acc[jj] = s;
    }
    bf16x8 v;
    #pragma unroll
    for (int jj = 0; jj < 8; ++jj) v[jj] = f2bf(acc[jj]);
    *(bf16x8*)(qkfrag + (((long)b * 16 + (l >> 2)) * 64 + (l & 3) * 16 + hs) * 8) = v;
}

// ---------- persistent fused: double-buffered kswz, 3 barriers/chunk ----------
// launch_bounds (512,1): LDS (142KB) already pins 1 block/CU, so release the
// VGPR cap to 256 — full prefetch+fragment state fits without spills.
__global__ __launch_bounds__(512, 1) void k_fusedp(const float* __restrict__ key,
                                                   const unsigned short* __restrict__ qkfrag,
                                                   unsigned short* __restrict__ wexp,
                                                   float* __restrict__ ms, float* __restrict__ zs,
                                                   float* __restrict__ apart) {
    extern __shared__ __align__(16) char smem[];
    float* scr           = (float*)(smem + 131072);          // [2 eh][16 hs][68 p]
    unsigned short* wbf  = (unsigned short*)(smem + 139776); // [16 hs][72 p]
    float* fac_l         = (float*)(smem + 142080);          // [16]
    float* mrun_l        = (float*)(smem + 142144);          // [16]

    int pcg = blockIdx.x, b = blockIdx.y;
    int t = threadIdx.x, wv = t >> 6, l = t & 63;
    int rt = wv >> 1, eh = wv & 1;
    int prow = rt * 16 + (l & 15);
    int xorv = KXOR(prow);
    int hi = t >> 7;          // row = 4r + hi
    int col4 = t & 127;       // f32x4 column within row

    if (t < 16) mrun_l[t] = -3.0e38f;

    // preload qk B-fragments for this wave's e-half
    bf16x8 qfr[8];
    {
        const bf16x8* qf = (const bf16x8*)(qkfrag + (long)b * 16 * 64 * 8);
        #pragma unroll
        for (int s = 0; s < 8; ++s) qfr[s] = qf[(eh * 8 + s) * 64 + l];
    }

    const float* kchunk = key + ((long)b * P_ + pcg * 512) * E_;

    // prologue: stage chunk 0 (linear contiguous)
    f32x4 x[16];
    #pragma unroll
    for (int r = 0; r < 16; ++r)
        x[r] = *(const f32x4*)(kchunk + (long)(r * 512 + t) * 4);

    f32x4 accp[4];
    #pragma unroll
    for (int i = 0; i < 4; ++i) accp[i] = {0.f, 0.f, 0.f, 0.f};

    for (int c = 0; c < 8; ++c) {
        unsigned short* kz = (unsigned short*)(smem + (c & 1) * 65536);
        // ---- A1: convert + write kz (lane-linear, conflict-free) ----
        #pragma unroll
        for (int r = 0; r < 16; ++r) {
            int row = 4 * r + hi;
            int xr = KXOR(row);
            bf16x4 wb;
            wb[0] = f2bf(x[r][0]); wb[1] = f2bf(x[r][1]);
            wb[2] = f2bf(x[r][2]); wb[3] = f2bf(x[r][3]);
            *(bf16x4*)(kz + row * 512 + ((col4 * 4) ^ xr)) = wb;
        }
        // ---- issue chunk c+1 loads (contiguous; stream under A2/B/C) ----
        if (c < 7) {
            const float* kn = kchunk + (long)(c + 1) * 64 * E_;
            #pragma unroll
            for (int r = 0; r < 16; ++r)
                x[r] = *(const f32x4*)(kn + (long)(r * 512 + t) * 4);
        }
        BAR();

        // ---- A2: QK^T from LDS A-frags ----
        {
            f32x4 acc = {0.f, 0.f, 0.f, 0.f};
            #pragma unroll
            for (int s = 0; s < 8; ++s) {
                int e8 = eh * 256 + (l >> 4) * 8 + s * 32;
                bf16x8 a = *(const bf16x8*)(kz + prow * 512 + (e8 ^ xorv));
                acc = __builtin_amdgcn_mfma_f32_16x16x32_bf16(a, qfr[s], acc, 0, 0, 0);
            }
            #pragma unroll
            for (int r = 0; r < 4; ++r)
                scr[eh * 1088 + (l & 15) * 68 + rt * 16 + (l >> 4) * 4 + r] = acc[r];
        }
        BAR();

        // ---- B: chunk softmax stats + wexp bf16 + wbf bf16 (running-max scaled) ----
        {
            int hs = t >> 5, i = t & 31;
            const float* s0p = scr + hs * 68 + i * 2;
            const float* s1p = s0p + 1088;
            float v0 = s0p[0] + s1p[0];
            float v1 = s0p[1] + s1p[1];
            float m = fmaxf(v0, v1);
            #pragma unroll
            for (int o = 16; o > 0; o >>= 1) m = fmaxf(m, __shfl_xor(m, o));
            float e0v = expf(v0 - m), e1v = expf(v1 - m);
            float z = e0v + e1v;
            #pragma unroll
            for (int o = 16; o > 0; o >>= 1) z += __shfl_xor(z, o);
            float mold = mrun_l[hs];
            float mnew = fmaxf(mold, m);
            float wsc = expf(m - mnew);
            if (i == 0) {
                mrun_l[hs] = mnew;
                fac_l[hs] = expf(mold - mnew);
                ms[((long)(pcg * 8 + c) * B_ + b) * 16 + hs] = m;
                zs[((long)(pcg * 8 + c) * B_ + b) * 16 + hs] = z;
            }
            unsigned wpack = (unsigned)(unsigned short)f2bf(e0v)
                           | ((unsigned)(unsigned short)f2bf(e1v) << 16);
            *(unsigned*)(wexp + ((long)b * 16 + hs) * P_ + pcg * 512 + c * 64 + i * 2) = wpack;
            unsigned lo = (unsigned short)f2bf(e0v * wsc);
            unsigned hi2 = (unsigned short)f2bf(e1v * wsc);
            *(unsigned*)(wbf + hs * 72 + i * 2) = lo | (hi2 << 16);
        }
        BAR();

        // ---- C: PV-MFMA from LDS, reg accum with online rescale (no trailing BAR) ----
        {
            f32x4 frv;
            frv[0] = fac_l[(l >> 4) * 4 + 0];
            frv[1] = fac_l[(l >> 4) * 4 + 1];
            frv[2] = fac_l[(l >> 4) * 4 + 2];
            frv[3] = fac_l[(l >> 4) * 4 + 3];
            const unsigned short* wrow = wbf + (l & 15) * 72;
            bf16x8 af0 = *(const bf16x8*)(wrow + (l >> 4) * 8);
            bf16x8 af1 = *(const bf16x8*)(wrow + 32 + (l >> 4) * 8);
            #pragma unroll
            for (int tile = 0; tile < 4; ++tile) {
                accp[tile] = accp[tile] * frv;
                int e = wv * 64 + tile * 16 + (l & 15);
                #pragma unroll
                for (int ks = 0; ks < 2; ++ks) {
                    int pbase = ks * 32 + (l >> 4) * 8;
                    bf16x8 af = ks ? af1 : af0;
                    int xc = ((pbase & 8) << 1) ^ ((pbase & 16) >> 1);
                    bf16x8 bfv;
                    #pragma unroll
                    for (int j = 0; j < 8; ++j)
                        bfv[j] = (short)kz[(pbase + j) * 512 + (e ^ (j << 3) ^ xc)];
                    accp[tile] = __builtin_amdgcn_mfma_f32_16x16x32_bf16(af, bfv, accp[tile], 0, 0, 0);
                }
            }
        }
        // no barrier: next A1 writes the other kswz buffer
    }

    // ---- epilogue: write group partials (relative to group running max) ----
    {
        long abase = ((long)pcg * B_ + b) * 16 * E_;
        #pragma unroll
        for (int tile = 0; tile < 4; ++tile) {
            int e = wv * 64 + tile * 16 + (l & 15);
            #pragma unroll
            for (int r = 0; r < 4; ++r)
                apart[abase + (long)((l >> 4) * 4 + r) * E_ + e] = accp[tile][r];
        }
    }
}

// ---------- combine: global stats, out1 (diff), attk from 4 groups, OV, RMS -> on ----------
__global__ __launch_bounds__(256) void k_comb(const unsigned short* __restrict__ wexp,
                                              const float* __restrict__ ms, const float* __restrict__ zs,
                                              const float* __restrict__ apart,
                                              const float* __restrict__ lq1, const float* __restrict__ lk1,
                                              const float* __restrict__ lq2, const float* __restrict__ lk2,
                                              const float* __restrict__ Wv, const float* __restrict__ rmsw,
                                              float* __restrict__ out1, float* __restrict__ on) {
    int h = blockIdx.x, b = blockIdx.y, t = threadIdx.x;
    __shared__ float lam_s;
    __shared__ float mc0s[NC_], mc1s[NC_], zc0s[NC_], zc1s[NC_];
    __shared__ float c0s[NC_], c1s[NC_];
    __shared__ float attk[E_];
    __shared__ float onred[2][128];
    __shared__ float red[4];
    int hs0 = 2 * h, hs1 = 2 * h + 1;
    if (t < 64) {
        float v1 = lq1[t] * lk1[t];
        float v2 = lq2[t] * lk2[t];
        #pragma unroll
        for (int o = 32; o > 0; o >>= 1) { v1 += __shfl_xor(v1, o); v2 += __shfl_xor(v2, o); }
        if (t == 0) lam_s = expf(v1) - expf(v2) + LAMBDA_INIT_C;
    }
    if (t >= 64 && t < 64 + NC_) {
        int c = t - 64;
        mc0s[c] = ms[((long)c * B_ + b) * 16 + hs0];
        mc1s[c] = ms[((long)c * B_ + b) * 16 + hs1];
        zc0s[c] = zs[((long)c * B_ + b) * 16 + hs0];
        zc1s[c] = zs[((long)c * B_ + b) * 16 + hs1];
    }
    __syncthreads();
    float m0 = -3.0e38f, m1 = -3.0e38f;
    #pragma unroll
    for (int c = 0; c < NC_; ++c) { m0 = fmaxf(m0, mc0s[c]); m1 = fmaxf(m1, mc1s[c]); }
    float z0 = 0.f, z1 = 0.f;
    #pragma unroll
    for (int c = 0; c < NC_; ++c) {
        z0 += zc0s[c] * expf(mc0s[c] - m0);
        z1 += zc1s[c] * expf(mc1s[c] - m1);
    }
    float lam = lam_s;
    float i0 = 1.f / (z0 + 1e-20f);
    float i1 = lam / (z1 + 1e-20f);
    if (t < NC_) {
        c0s[t] = expf(mc0s[t] - m0) * i0;
        c1s[t] = expf(mc1s[t] - m1) * i1;
    }
    __syncthreads();
    // out1 = diff (wexp bf16-packed; p0 even and p0+1 share the same 64-chunk)
    const unsigned* w0p = (const unsigned*)(wexp + ((long)b * 16 + hs0) * P_);
    const unsigned* w1p = (const unsigned*)(wexp + ((long)b * 16 + hs1) * P_);
    float* dst = out1 + ((long)b * H_ + h) * P_;
    #pragma unroll
    for (int k4 = 0; k4 < 4; ++k4) {
        int idx = k4 * 256 + t;          // u32 index, p0 = 2*idx
        unsigned w0 = w0p[idx], w1 = w1p[idx];
        int p0 = idx * 2;
        int cc = p0 >> 6;
        dst[p0]     = bf2f((unsigned short)w0) * c0s[cc] - bf2f((unsigned short)w1) * c1s[cc];
        dst[p0 + 1] = bf2f((unsigned short)(w0 >> 16)) * c0s[cc]
                    - bf2f((unsigned short)(w1 >> 16)) * c1s[cc];
    }
    // group weights: m_g = max of the group's 8 chunk maxes
    float cg0[NG_], cg1[NG_];
    #pragma unroll
    for (int g = 0; g < NG_; ++g) {
        float mg0 = -3.0e38f, mg1 = -3.0e38f;
        #pragma unroll
        for (int q = 0; q < 8; ++q) {
            mg0 = fmaxf(mg0, mc0s[g * 8 + q]);
            mg1 = fmaxf(mg1, mc1s[g * 8 + q]);
        }
        cg0[g] = expf(mg0 - m0) * i0;
        cg1[g] = expf(mg1 - m1) * i1;
    }
    #pragma unroll
    for (int k = 0; k < 2; ++k) {
        int e = k * 256 + t;
        float s = 0.f;
        #pragma unroll
        for (int g = 0; g < NG_; ++g) {
            s += cg0[g] * apart[(((long)g * B_ + b) * 16 + hs0) * E_ + e]
               - cg1[g] * apart[(((long)g * B_ + b) * 16 + hs1) * E_ + e];
        }
        attk[e] = s;
    }
    __syncthreads();
    // OV + RMS (8-deep ILP)
    int j = t & 127, half = t >> 7;
    const float* w = Wv + (long)(half * 256) * D_ + h * 128 + j;
    const float* aa = attk + half * 256;
    float s[8] = {0.f,0.f,0.f,0.f,0.f,0.f,0.f,0.f};
    #pragma unroll 4
    for (int e = 0; e < 256; e += 8) {
        #pragma unroll
        for (int k = 0; k < 8; ++k) s[k] += aa[e + k] * w[(long)(e + k) * D_];
    }
    onred[half][j] = ((s[0]+s[1])+(s[2]+s[3])) + ((s[4]+s[5])+(s[6]+s[7]));
    __syncthreads();
    float v = 0.f;
    if (t < 128) v = onred[0][t] + onred[1][t];
    float sq = v * v;
    int wv2 = t >> 6, ln = t & 63;
    #pragma unroll
    for (int o = 32; o > 0; o >>= 1) sq += __shfl_xor(sq, o);
    if (ln == 0) red[wv2] = sq;
    __syncthreads();
    float tot = red[0] + red[1];
    float scale = rsqrtf(tot * (1.f / 128.f) + 1e-5f) * (1.f - LAMBDA_INIT_C);
    if (t < 128) on[(long)b * D_ + h * 128 + t] = v * scale * rmsw[t];
}

// ---------- Wo split-K partials ----------
__global__ __launch_bounds__(256) void k_wo(const float* __restrict__ on,
                                            const float* __restrict__ Wo,
                                            float* __restrict__ wop) {
    int kc = blockIdx.x >> 1, oc = blockIdx.x & 1, b = blockIdx.y;
    int t = threadIdx.x;
    __shared__ float sh[256];
    sh[t] = on[(long)b * D_ + kc * 256 + t];
    __syncthreads();
    int o = oc * 256 + t;
    const float* w = Wo + (long)(kc * 256) * 512 + o;
    float s[8] = {0.f,0.f,0.f,0.f,0.f,0.f,0.f,0.f};
    #pragma unroll 4
    for (int k = 0; k < 256; k += 8) {
        #pragma unroll
        for (int q = 0; q < 8; ++q) s[q] += sh[k + q] * w[(long)(k + q) * 512];
    }
    wop[((long)kc * B_ + b) * 512 + o] = ((s[0]+s[1])+(s[2]+s[3])) + ((s[4]+s[5])+(s[6]+s[7]));
}

// ---------- reduce Wo partials -> out0 ----------
__global__ __launch_bounds__(256) void k_wored(const float* __restrict__ wop,
                                               float* __restrict__ out0) {
    int b = blockIdx.x, t = threadIdx.x;
    #pragma unroll
    for (int i = 0; i < 2; ++i) {
        int o = i * 256 + t;
        float s = 0.f;
        #pragma unroll
        for (int kc = 0; kc < 4; ++kc) s += wop[((long)kc * B_ + b) * 512 + o];
        out0[(long)b * 512 + o] = s;
    }
}

extern "C" void kernel_launch(void* const* d_in, const int* in_sizes, int n_in,
                              void* d_out, int out_size, void* d_ws, size_t ws_size,
                              hipStream_t stream) {
    const float* query = (const float*)d_in[0];
    const float* key   = (const float*)d_in[1];
    const float* Wq    = (const float*)d_in[2];
    const float* Wk    = (const float*)d_in[3];
    const float* Wv    = (const float*)d_in[4];
    const float* Wo    = (const float*)d_in[5];
    const float* lq1   = (const float*)d_in[6];
    const float* lk1   = (const float*)d_in[7];
    const float* lq2   = (const float*)d_in[8];
    const float* lk2   = (const float*)d_in[9];
    const float* rmsw  = (const float*)d_in[10];

    float* out0 = (float*)d_out;           // [64,1,512]
    float* out1 = out0 + B_ * E_;          // diff_attn [64,8,1,2048]

    // ws (floats): qkfrag slack [262144] | wexp u16 (=1048576 f) |
    //              apart [4][64][16][512] | ms[32][64][16] | zs | on | wop
    unsigned short* qkfrag = (unsigned short*)d_ws;
    unsigned short* wexp = (unsigned short*)((float*)d_ws + 262144);
    float* apart = (float*)d_ws + 262144 + 1048576;
    float* ms    = apart + (long)NG_ * B_ * 16 * E_;       // +2097152
    float* zs    = ms + NC_ * B_ * 16;
    float* on    = zs + NC_ * B_ * 16;
    float* wop   = on + B_ * D_;

    hipFuncSetAttribute((const void*)k_fusedp,
                        hipFuncAttributeMaxDynamicSharedMemorySize, SMEM_FUSED);

    hipLaunchKernelGGL(k_qproj,  dim3(4, B_),   dim3(256), 0, stream, query, Wq, Wk, qkfrag);
    hipLaunchKernelGGL(k_fusedp, dim3(NG_, B_), dim3(512), SMEM_FUSED, stream,
                       key, qkfrag, wexp, ms, zs, apart);
    hipLaunchKernelGGL(k_comb,   dim3(H_, B_),  dim3(256), 0, stream, wexp, ms, zs, apart,
                       lq1, lk1, lq2, lk2, Wv, rmsw, out1, on);
    hipLaunchKernelGGL(k_wo,     dim3(8, B_),   dim3(256), 0, stream, on, Wo, wop);
    hipLaunchKernelGGL(k_wored,  dim3(B_),      dim3(256), 0, stream, wop, out0);
}